// Round 3
// baseline (108591.260 us; speedup 1.0000x reference)
//
#include <hip/hip_runtime.h>
#include <stdint.h>

#define TSTEPS   4096
#define NEG_VAL  -1000000000.0f

typedef _Float16 h2    __attribute__((ext_vector_type(2)));
typedef _Float16 f16x8 __attribute__((ext_vector_type(8)));

// ---------------- workspace layout (bytes) ----------------
#define GI0_OFF   0                                   // T*1536*4 = 25165824
#define H1_OFF    (TSTEPS*1536*4)                     // T*512*4  = 8388608
#define RING0_OFF (H1_OFF + TSTEPS*512*4)             // 32*512*8 = 131072
#define GIR_OFF   (RING0_OFF + 32*512*8)              // 32*1536*8= 393216
#define PROG_OFF  (GIR_OFF + (size_t)32*1536*8)       // 4*64B
#define WS_NEED   ((size_t)PROG_OFF + 256)

// ---------------- helpers ----------------
static __device__ __forceinline__ unsigned long long ld_a64(const unsigned long long* p){
  return __hip_atomic_load(p, __ATOMIC_RELAXED, __HIP_MEMORY_SCOPE_AGENT);
}
static __device__ __forceinline__ void st_a64(unsigned long long* p, unsigned long long v){
  __hip_atomic_store(p, v, __ATOMIC_RELAXED, __HIP_MEMORY_SCOPE_AGENT);
}
static __device__ __forceinline__ unsigned ld_u32(const unsigned* p){
  return __hip_atomic_load(p, __ATOMIC_RELAXED, __HIP_MEMORY_SCOPE_AGENT);
}
static __device__ __forceinline__ void st_u32(unsigned* p, unsigned v){
  __hip_atomic_store(p, v, __ATOMIC_RELAXED, __HIP_MEMORY_SCOPE_AGENT);
}
static __device__ __forceinline__ float sigmoidf_(float x){
  return 1.0f / (1.0f + __expf(-x));
}
static __device__ __forceinline__ float tanhf_(float x){
  float ax = fabsf(x);
  float e  = __expf(-2.0f*ax);
  float t  = (1.0f - e) / (1.0f + e);
  return copysignf(t, x);
}
static __device__ __forceinline__ float spin_word(const unsigned long long* p, unsigned want, long* bd){
  unsigned long long v;
  for(;;){ v = ld_a64(p); if ((unsigned)(v>>32) == want) break; if (--(*bd) < 0) break; }
  return __uint_as_float((unsigned)v);
}
template<int CTRL>
static __device__ __forceinline__ float dppx(float x){
  return __int_as_float(__builtin_amdgcn_update_dpp(0, __float_as_int(x), CTRL, 0xF, 0xF, true));
}
#define DPP_XOR1 0xB1   /* quad_perm(1,0,3,2) */
#define DPP_XOR2 0x4E   /* quad_perm(2,3,0,1) */

#if __has_builtin(__builtin_amdgcn_fdot2)
#define FDOT2(a,b,c) __builtin_amdgcn_fdot2((a),(b),(c),false)
#else
static __device__ __forceinline__ float FDOT2(h2 a, h2 b, float c){
  return c + (float)a[0]*(float)b[0] + (float)a[1]*(float)b[1];
}
#endif

// swizzled f16 h-buffer: block (o>>6) at byte (o>>6)*144, elem (o&63)*2.
// ds_read_b128 at  b*144 + cc*16 : bank-quad (9b+cc)%8 distinct per b -> conflict-free.

// ---------------- persistent 2-layer GRU scan: 4 WGs x 1024 ----------------
// WG0: layer0 core (Whh0 in VGPR, no polling).  WG1: layer1 core (Whh1, h1 local).
// WG2,3: helpers computing gi1 = Wih1 h0 + bih1, pipelined on the h0 ring.
__global__ __launch_bounds__(1024,1) void gru_scan(
    const float* __restrict__ gi0,
    const float* __restrict__ hprev,
    const float* __restrict__ Whh0,
    const float* __restrict__ Wih1,
    const float* __restrict__ Whh1,
    const float* __restrict__ bhh0,
    const float* __restrict__ bih1,
    const float* __restrict__ bhh1,
    float* __restrict__ H1hist,
    unsigned long long* ring0,
    unsigned long long* gir,
    unsigned* prog,
    float* __restrict__ hnext)
{
  const int role = blockIdx.x;
  const int tid  = threadIdx.x;
  const int p    = tid & 7;        // lane within 8-group (== col-block b)
  const int g    = tid >> 3;       // row group 0..127
  const int q    = tid & 3;        // output slot within group
  const int o    = g + 128*q;      // owned output index (dup at p and p+4)

  __shared__ __align__(16) char smem[16384];
  long bd = 1L<<22;

  if (role == 0){
    // ===================== layer 0 core =====================
    h2 w[12][32];
    #pragma unroll
    for (int j=0;j<12;++j){
      const float4* wp = (const float4*)(Whh0 + (size_t)(g + 128*j)*512 + p*64);
      #pragma unroll
      for (int c=0;c<16;++c){
        float4 v = wp[c];
        w[j][2*c]   = h2{(_Float16)v.x,(_Float16)v.y};
        w[j][2*c+1] = h2{(_Float16)v.z,(_Float16)v.w};
      }
    }
    float hreg = hprev[o];
    const float br = bhh0[o], bz = bhh0[512+o], bn = bhh0[1024+o];
    if (tid < 512)
      *(_Float16*)(smem + (tid>>6)*144 + (tid&63)*2) = (_Float16)hprev[tid];
    __syncthreads();

    for (int t=0; t<TSTEPS; ++t){
      if (tid==4 && (t&7)==0 && t>=16){      // ring0 overwrite safety vs helpers
        const int need = t-16;
        for(;;){
          unsigned a = ld_u32(prog+32), c = ld_u32(prog+48);
          if ((int)(a<c?a:c) >= need) break;
          if (--bd < 0) break;
        }
      }
      const float gr = gi0[(size_t)t*1536 + o];
      const float gz = gi0[(size_t)t*1536 + 512 + o];
      const float gn = gi0[(size_t)t*1536 + 1024 + o];

      float acc[12] = {0,0,0,0,0,0,0,0,0,0,0,0};
      const char* hb = smem + (t&1)*1152 + p*144;
      #pragma unroll
      for (int cc=0;cc<8;++cc){
        f16x8 hv = *(const f16x8*)(hb + cc*16);
        h2 v0 = __builtin_shufflevector(hv,hv,0,1);
        h2 v1 = __builtin_shufflevector(hv,hv,2,3);
        h2 v2 = __builtin_shufflevector(hv,hv,4,5);
        h2 v3 = __builtin_shufflevector(hv,hv,6,7);
        #pragma unroll
        for (int j=0;j<12;++j){
          acc[j] = FDOT2(w[j][4*cc],   v0, acc[j]);
          acc[j] = FDOT2(w[j][4*cc+1], v1, acc[j]);
          acc[j] = FDOT2(w[j][4*cc+2], v2, acc[j]);
          acc[j] = FDOT2(w[j][4*cc+3], v3, acc[j]);
        }
      }
      // multiplexed tree reduce over the 8 col-blocks
      float b6[6];
      #pragma unroll
      for (int i=0;i<6;++i){
        float keep = (p&1)? acc[2*i+1] : acc[2*i];
        float send = (p&1)? acc[2*i]   : acc[2*i+1];
        b6[i] = keep + dppx<DPP_XOR1>(send);
      }
      float c3[3];
      #pragma unroll
      for (int i=0;i<3;++i){
        float keep = (p&2)? b6[2*i+1] : b6[2*i];
        float send = (p&2)? b6[2*i]   : b6[2*i+1];
        c3[i] = keep + dppx<DPP_XOR2>(send);
      }
      const float d0 = c3[0] + __shfl_xor(c3[0],4,64);   // r-row (o)
      const float d1 = c3[1] + __shfl_xor(c3[1],4,64);   // z-row (512+o)
      const float d2 = c3[2] + __shfl_xor(c3[2],4,64);   // n-row (1024+o)

      const float r = sigmoidf_(gr + d0 + br);
      const float z = sigmoidf_(gz + d1 + bz);
      const float n = tanhf_(gn + r*(d2 + bn));
      const float h = (1.f - z)*n + z*hreg;
      hreg = h;
      if ((tid&4)==0){
        *(_Float16*)(smem + ((t+1)&1)*1152 + (o>>6)*144 + (o&63)*2) = (_Float16)h;
        st_a64(ring0 + (size_t)(t&31)*512 + o,
               ((unsigned long long)(unsigned)(t+1)<<32) | __float_as_uint(h));
        if (t==TSTEPS-1) hnext[o] = h;
      }
      __syncthreads();
    }
  } else if (role == 1){
    // ===================== layer 1 core =====================
    h2 w[12][32];
    #pragma unroll
    for (int j=0;j<12;++j){
      const float4* wp = (const float4*)(Whh1 + (size_t)(g + 128*j)*512 + p*64);
      #pragma unroll
      for (int c=0;c<16;++c){
        float4 v = wp[c];
        w[j][2*c]   = h2{(_Float16)v.x,(_Float16)v.y};
        w[j][2*c+1] = h2{(_Float16)v.z,(_Float16)v.w};
      }
    }
    float* gilds = (float*)(smem + 4096);    // [2][1536] f32
    float hreg = hprev[512+o];
    const float br = bhh1[o], bz = bhh1[512+o], bn = bhh1[1024+o];
    if (tid < 512)
      *(_Float16*)(smem + (tid>>6)*144 + (tid&63)*2) = (_Float16)hprev[512+tid];
    if (tid < 768){                          // prologue: gi(0)
      gilds[tid]     = spin_word(gir + tid,       1u, &bd);
      gilds[768+tid] = spin_word(gir + 768 + tid, 1u, &bd);
    }
    __syncthreads();

    for (int s=0; s<TSTEPS; ++s){
      float acc[12] = {0,0,0,0,0,0,0,0,0,0,0,0};
      const char* hb = smem + (s&1)*1152 + p*144;
      #pragma unroll
      for (int cc=0;cc<8;++cc){
        f16x8 hv = *(const f16x8*)(hb + cc*16);
        h2 v0 = __builtin_shufflevector(hv,hv,0,1);
        h2 v1 = __builtin_shufflevector(hv,hv,2,3);
        h2 v2 = __builtin_shufflevector(hv,hv,4,5);
        h2 v3 = __builtin_shufflevector(hv,hv,6,7);
        #pragma unroll
        for (int j=0;j<12;++j){
          acc[j] = FDOT2(w[j][4*cc],   v0, acc[j]);
          acc[j] = FDOT2(w[j][4*cc+1], v1, acc[j]);
          acc[j] = FDOT2(w[j][4*cc+2], v2, acc[j]);
          acc[j] = FDOT2(w[j][4*cc+3], v3, acc[j]);
        }
      }
      float b6[6];
      #pragma unroll
      for (int i=0;i<6;++i){
        float keep = (p&1)? acc[2*i+1] : acc[2*i];
        float send = (p&1)? acc[2*i]   : acc[2*i+1];
        b6[i] = keep + dppx<DPP_XOR1>(send);
      }
      float c3[3];
      #pragma unroll
      for (int i=0;i<3;++i){
        float keep = (p&2)? b6[2*i+1] : b6[2*i];
        float send = (p&2)? b6[2*i]   : b6[2*i+1];
        c3[i] = keep + dppx<DPP_XOR2>(send);
      }
      const float d0 = c3[0] + __shfl_xor(c3[0],4,64);
      const float d1 = c3[1] + __shfl_xor(c3[1],4,64);
      const float d2 = c3[2] + __shfl_xor(c3[2],4,64);

      if (s < TSTEPS-1 && tid < 768){        // poll-ahead gi(s+1), other buffer
        const size_t base = (size_t)((s+1)&31)*1536;
        float* gdst = gilds + ((s+1)&1)*1536;
        gdst[tid]     = spin_word(gir + base + tid,       (unsigned)(s+2), &bd);
        gdst[768+tid] = spin_word(gir + base + 768 + tid, (unsigned)(s+2), &bd);
      }
      if (tid==900 && (s&7)==0) st_u32(prog+16, (unsigned)s);

      const float* gsrc = gilds + (s&1)*1536;
      const float r = sigmoidf_(gsrc[o]      + d0 + br);
      const float z = sigmoidf_(gsrc[512+o]  + d1 + bz);
      const float n = tanhf_(gsrc[1024+o] + r*(d2 + bn));
      const float h = (1.f - z)*n + z*hreg;
      hreg = h;
      if ((tid&4)==0){
        *(_Float16*)(smem + ((s+1)&1)*1152 + (o>>6)*144 + (o&63)*2) = (_Float16)h;
        H1hist[(size_t)s*512 + o] = h;
        if (s==TSTEPS-1) hnext[512+o] = h;
      }
      __syncthreads();
    }
  } else {
    // ===================== gi1 helpers (role 2,3) =====================
    const int hh = role - 2;                 // rows [768*hh, 768*hh+768)
    h2 w[6][32];
    #pragma unroll
    for (int k=0;k<6;++k){
      const float4* wp = (const float4*)(Wih1 + (size_t)(768*hh + g + 128*k)*512 + p*64);
      #pragma unroll
      for (int c=0;c<16;++c){
        float4 v = wp[c];
        w[k][2*c]   = h2{(_Float16)v.x,(_Float16)v.y};
        w[k][2*c+1] = h2{(_Float16)v.z,(_Float16)v.w};
      }
    }
    float bia[3];
    #pragma unroll
    for (int i=0;i<3;++i) bia[i] = bih1[768*hh + g + 128*((p&1)+2*i)];
    if (tid < 512)                            // prologue: h0(0)
      *(_Float16*)(smem + (tid>>6)*144 + (tid&63)*2) =
        (_Float16)spin_word(ring0 + tid, 1u, &bd);
    __syncthreads();

    for (int s=0; s<TSTEPS; ++s){
      float acc[6] = {0,0,0,0,0,0};
      const char* hb = smem + (s&1)*1152 + p*144;
      #pragma unroll
      for (int cc=0;cc<8;++cc){
        f16x8 hv = *(const f16x8*)(hb + cc*16);
        h2 v0 = __builtin_shufflevector(hv,hv,0,1);
        h2 v1 = __builtin_shufflevector(hv,hv,2,3);
        h2 v2 = __builtin_shufflevector(hv,hv,4,5);
        h2 v3 = __builtin_shufflevector(hv,hv,6,7);
        #pragma unroll
        for (int k=0;k<6;++k){
          acc[k] = FDOT2(w[k][4*cc],   v0, acc[k]);
          acc[k] = FDOT2(w[k][4*cc+1], v1, acc[k]);
          acc[k] = FDOT2(w[k][4*cc+2], v2, acc[k]);
          acc[k] = FDOT2(w[k][4*cc+3], v3, acc[k]);
        }
      }
      float b3[3];
      #pragma unroll
      for (int i=0;i<3;++i){
        float keep = (p&1)? acc[2*i+1] : acc[2*i];
        float send = (p&1)? acc[2*i]   : acc[2*i+1];
        b3[i] = keep + dppx<DPP_XOR1>(send);
      }
      #pragma unroll
      for (int i=0;i<3;++i) b3[i] += dppx<DPP_XOR2>(b3[i]);
      #pragma unroll
      for (int i=0;i<3;++i) b3[i] += __shfl_xor(b3[i],4,64);

      if ((p&6)==0){                          // p in {0,1}: publish 3 rows
        #pragma unroll
        for (int i=0;i<3;++i){
          const int row = 768*hh + g + 128*((p&1)+2*i);
          st_a64(gir + (size_t)(s&31)*1536 + row,
                 ((unsigned long long)(unsigned)(s+1)<<32) |
                 __float_as_uint(b3[i] + bia[i]));
        }
      }
      if (tid==5 && (s&7)==0) st_u32(prog + (2+hh)*16, (unsigned)s);
      if (tid==4 && (s&7)==0 && s>=16){       // gi-ring overwrite safety vs L1
        const int need = s-16;
        for(;;){ unsigned a = ld_u32(prog+16); if ((int)a >= need) break; if (--bd<0) break; }
      }
      if (s < TSTEPS-1 && tid < 512){         // poll-ahead h0(s+1)
        *(_Float16*)(smem + ((s+1)&1)*1152 + (tid>>6)*144 + (tid&63)*2) =
          (_Float16)spin_word(ring0 + (size_t)((s+1)&31)*512 + tid, (unsigned)(s+2), &bd);
      }
      __syncthreads();
    }
  }
}

// ---------------- tiled fp32 GEMM: C[m][n] = sum_k A[m][k]*B[n][k] + bias[n] ----------------
template<int EPI>
__global__ __launch_bounds__(256) void gemm_nt(
    const float* __restrict__ A, int lda,
    const float* __restrict__ B, int ldb,
    float* __restrict__ C, int ldc,
    const float* __restrict__ bias,
    const int* __restrict__ mask,
    int K)
{
  __shared__ __align__(16) float As[32][68];
  __shared__ __align__(16) float Bs[32][68];
  const int bm = blockIdx.y*64, bn = blockIdx.x*64;
  const int tid = threadIdx.x;
  const int tm = tid>>4, tn = tid&15;
  float acc[4][4] = {};
  const int m0 = tid>>2, kk0 = (tid&3)*8;
  for (int k0=0; k0<K; k0+=32){
    #pragma unroll
    for (int j=0;j<8;++j) As[kk0+j][m0] = A[(size_t)(bm+m0)*lda + k0+kk0+j];
    #pragma unroll
    for (int j=0;j<8;++j) Bs[kk0+j][m0] = B[(size_t)(bn+m0)*ldb + k0+kk0+j];
    __syncthreads();
    #pragma unroll
    for (int kk=0;kk<32;++kk){
      const float4 av = *(const float4*)&As[kk][tm*4];
      const float4 bv = *(const float4*)&Bs[kk][tn*4];
      acc[0][0]=fmaf(av.x,bv.x,acc[0][0]); acc[0][1]=fmaf(av.x,bv.y,acc[0][1]);
      acc[0][2]=fmaf(av.x,bv.z,acc[0][2]); acc[0][3]=fmaf(av.x,bv.w,acc[0][3]);
      acc[1][0]=fmaf(av.y,bv.x,acc[1][0]); acc[1][1]=fmaf(av.y,bv.y,acc[1][1]);
      acc[1][2]=fmaf(av.y,bv.z,acc[1][2]); acc[1][3]=fmaf(av.y,bv.w,acc[1][3]);
      acc[2][0]=fmaf(av.z,bv.x,acc[2][0]); acc[2][1]=fmaf(av.z,bv.y,acc[2][1]);
      acc[2][2]=fmaf(av.z,bv.z,acc[2][2]); acc[2][3]=fmaf(av.z,bv.w,acc[2][3]);
      acc[3][0]=fmaf(av.w,bv.x,acc[3][0]); acc[3][1]=fmaf(av.w,bv.y,acc[3][1]);
      acc[3][2]=fmaf(av.w,bv.z,acc[3][2]); acc[3][3]=fmaf(av.w,bv.w,acc[3][3]);
    }
    __syncthreads();
  }
  #pragma unroll
  for (int i=0;i<4;++i){
    #pragma unroll
    for (int j=0;j<4;++j){
      const int mm = bm + tm*4 + i, cc = bn + tn*4 + j;
      float v = acc[i][j] + bias[cc];
      if (EPI){
        v = fmaxf(v, 0.f);
        if (mask[cc] == 0) v = NEG_VAL;
      }
      C[(size_t)mm*ldc + cc] = v;
    }
  }
}

// ---------------- launch ----------------
extern "C" void kernel_launch(void* const* d_in, const int* in_sizes, int n_in,
                              void* d_out, int out_size, void* d_ws, size_t ws_size,
                              hipStream_t stream)
{
  const float* state = (const float*)d_in[0];   // (4096, 129)
  const float* hprev = (const float*)d_in[1];   // (2, 512)
  const int*   mask  = (const int*)d_in[2];     // (64, 64)
  const float* Wih0  = (const float*)d_in[3];   // (1536, 128)
  const float* Whh0  = (const float*)d_in[4];   // (1536, 512)
  const float* bih0  = (const float*)d_in[5];
  const float* bhh0  = (const float*)d_in[6];
  const float* Wih1  = (const float*)d_in[7];   // (1536, 512)
  const float* Whh1  = (const float*)d_in[8];   // (1536, 512)
  const float* bih1  = (const float*)d_in[9];
  const float* bhh1  = (const float*)d_in[10];
  const float* Wfc   = (const float*)d_in[11];  // (4096, 512)
  const float* bfc   = (const float*)d_in[12];

  if (ws_size < WS_NEED) return;   // fail loudly via poisoned output

  float* out = (float*)d_out;
  char*  ws  = (char*)d_ws;
  float* gi0 = (float*)(ws + GI0_OFF);
  float* H1  = (float*)(ws + H1_OFF);
  unsigned long long* ring0 = (unsigned long long*)(ws + RING0_OFF);
  unsigned long long* gir   = (unsigned long long*)(ws + GIR_OFF);
  unsigned* prog = (unsigned*)(ws + PROG_OFF);

  // reset rings + progress each call (stale tags from a previous replay would alias)
  (void)hipMemsetAsync(ws + RING0_OFF, 0, (size_t)(WS_NEED - RING0_OFF), stream);

  // gi0 = x @ Wih0^T + bih0   (M=4096, N=1536, K=128)
  {
    dim3 grid(1536/64, 4096/64);
    gemm_nt<0><<<grid, 256, 0, stream>>>(state+1, 129, Wih0, 128, gi0, 1536,
                                         bih0, nullptr, 128);
  }

  // sequential 2-layer GRU scan: 4 persistent WGs
  gru_scan<<<4, 1024, 0, stream>>>(gi0, hprev, Whh0, Wih1, Whh1,
                                   bhh0, bih1, bhh1,
                                   H1, ring0, gir, prog,
                                   out + (size_t)4096*4096);

  // logits = relu(H1 @ Wfc^T + bfc), masked   (M=4096, N=4096, K=512)
  {
    dim3 grid(4096/64, 4096/64);
    gemm_nt<1><<<grid, 256, 0, stream>>>(H1, 512, Wfc, 512, out, 4096,
                                         bfc, mask, 512);
  }
}

// Round 4
// 44637.396 us; speedup vs baseline: 2.4327x; 2.4327x over previous
//
#include <hip/hip_runtime.h>
#include <stdint.h>

#define TSTEPS  4096
#define NEG_VAL -1000000000.0f
#define L0N 8
#define L1N 16
#define SCANWG 24
#define GRIDWG 256

typedef _Float16 h2 __attribute__((ext_vector_type(2)));

// ---------------- workspace layout (bytes) ----------------
#define H1_OFF     0                                 // 4096*512*4 = 8388608
#define RING0_OFF  (TSTEPS*512*4)                    // 32*256*8 = 65536
#define RING1_OFF  (RING0_OFF + 32*256*8)            // 32*256*8 = 65536
#define PROGS_OFF  (RING1_OFF + 32*256*8)            // 24*64
#define PROGH_OFF  (PROGS_OFF + SCANWG*64)           // 16*64
#define TICK_OFF   (PROGH_OFF + L1N*64)              // 64
#define WS_NEED    ((size_t)TICK_OFF + 64)

// ---------------- helpers ----------------
static __device__ __forceinline__ unsigned long long ld_a64(const unsigned long long* p){
  return __hip_atomic_load(p, __ATOMIC_RELAXED, __HIP_MEMORY_SCOPE_AGENT);
}
static __device__ __forceinline__ void st_a64(unsigned long long* p, unsigned long long v){
  __hip_atomic_store(p, v, __ATOMIC_RELAXED, __HIP_MEMORY_SCOPE_AGENT);
}
static __device__ __forceinline__ unsigned ld_u32(const unsigned* p){
  return __hip_atomic_load(p, __ATOMIC_RELAXED, __HIP_MEMORY_SCOPE_AGENT);
}
static __device__ __forceinline__ void st_u32(unsigned* p, unsigned v){
  __hip_atomic_store(p, v, __ATOMIC_RELAXED, __HIP_MEMORY_SCOPE_AGENT);
}
static __device__ __forceinline__ unsigned ld_acq(const unsigned* p){
  return __hip_atomic_load(p, __ATOMIC_ACQUIRE, __HIP_MEMORY_SCOPE_AGENT);
}
static __device__ __forceinline__ void st_rel(unsigned* p, unsigned v){
  __hip_atomic_store(p, v, __ATOMIC_RELEASE, __HIP_MEMORY_SCOPE_AGENT);
}
static __device__ __forceinline__ float sigmoidf_(float x){
  return 1.0f / (1.0f + __expf(-x));
}
static __device__ __forceinline__ float tanhf_(float x){
  float ax = fabsf(x);
  float e  = __expf(-2.0f*ax);
  float t  = (1.0f - e) / (1.0f + e);
  return copysignf(t, x);
}
static __device__ __forceinline__ uint32_t pack2h(float a, float b){
  _Float16 ha = (_Float16)a, hb = (_Float16)b;
  unsigned short ua = __builtin_bit_cast(unsigned short, ha);
  unsigned short ub = __builtin_bit_cast(unsigned short, hb);
  return (uint32_t)ua | ((uint32_t)ub << 16);
}
static __device__ __forceinline__ h2 u2h2(uint32_t u){ return __builtin_bit_cast(h2, u); }

template<int CTRL>
static __device__ __forceinline__ float dppx(float x){
  return __int_as_float(__builtin_amdgcn_update_dpp(0, __float_as_int(x), CTRL, 0xF, 0xF, true));
}
#define DPP_B0 0x00
#define DPP_B1 0x55
#define DPP_B2 0xAA

#if __has_builtin(__builtin_amdgcn_fdot2)
#define FDOT2(a,b,c) __builtin_amdgcn_fdot2((a),(b),(c),false)
#else
static __device__ __forceinline__ float FDOT2(h2 a, h2 b, float c){
  return c + (float)a[0]*(float)b[0] + (float)a[1]*(float)b[1];
}
#endif

// ================= fused kernel: 256 WGs x 256 thr =================
// WG 0..7   : layer0 (64 h each; Whh0 row + Wih0 row per thread, in VGPRs)
// WG 8..23  : layer1 (32 h each; one row of Whh1 or Wih1 per thread)
// WG 24..255: FC GEMM (relu(H1 @ Wfc^T + bfc), masked), pipelined on progH
__global__ __launch_bounds__(256,1) void actor_fused(
    const float* __restrict__ state,
    const float* __restrict__ hprev,
    const int*   __restrict__ mask,
    const float* __restrict__ Wih0,
    const float* __restrict__ Whh0,
    const float* __restrict__ bih0,
    const float* __restrict__ bhh0,
    const float* __restrict__ Wih1,
    const float* __restrict__ Whh1,
    const float* __restrict__ bih1,
    const float* __restrict__ bhh1,
    const float* __restrict__ Wfc,
    const float* __restrict__ bfc,
    float* __restrict__ H1,
    unsigned long long* ring0,
    unsigned long long* ring1,
    unsigned* progS,
    unsigned* progH,
    unsigned* ticket,
    float* __restrict__ out,
    float* __restrict__ hnext)
{
  const int wg   = blockIdx.x;
  const int tid  = threadIdx.x;
  const int wv   = tid >> 6;
  const int lane = tid & 63;
  const int c    = lane & 3;
  const int rg   = lane >> 2;

  __shared__ __align__(16) char smem[17472];
  uint32_t* hb0 = (uint32_t*)smem;            // [2][256]
  uint32_t* hb1 = hb0 + 512;                  // [2][256]
  uint32_t* xb  = hb0 + 1024;                 // [2][64]
  long bd = 1L << 22;

  if (wg < L0N){
    // ===================== layer 0 =====================
    const int obase = wg*64;
    const int o = obase + wv*16 + rg;
    const int g = (c < 3) ? c : 2;
    h2 Wh[256]; h2 Wx[64];
    {
      const float4* r4 = (const float4*)(Whh0 + (size_t)(g*512 + o)*512);
      #pragma unroll
      for (int i=0;i<128;++i){
        float4 v = r4[i];
        Wh[2*i]   = h2{(_Float16)v.x,(_Float16)v.y};
        Wh[2*i+1] = h2{(_Float16)v.z,(_Float16)v.w};
      }
      const float4* x4 = (const float4*)(Wih0 + (size_t)(g*512 + o)*128);
      #pragma unroll
      for (int i=0;i<32;++i){
        float4 v = x4[i];
        Wx[2*i]   = h2{(_Float16)v.x,(_Float16)v.y};
        Wx[2*i+1] = h2{(_Float16)v.z,(_Float16)v.w};
      }
    }
    float hreg = hprev[o];
    const float bh = bhh0[g*512+o], bi = bih0[g*512+o];
    hb0[tid] = pack2h(hprev[2*tid], hprev[2*tid+1]);
    if (tid < 64) xb[tid] = pack2h(state[1+2*tid], state[2+2*tid]);

    for (int t=0; t<TSTEPS; ++t){
      if (t > 0){
        const unsigned long long* p = ring0 + (size_t)((t-1)&31)*256 + tid;
        unsigned long long v;
        for(;;){ v = ld_a64(p); if ((unsigned)(v>>32) == (unsigned)t) break;
                 if (--bd < 0) break; }
        hb0[(t&1)*256 + tid] = (uint32_t)v;
        if (tid < 64){
          const float* xr = state + (size_t)t*129 + 1;
          xb[(t&1)*64 + tid] = pack2h(xr[2*tid], xr[2*tid+1]);
        }
        if (tid == 0 && (t&7)==0 && t >= 32){
          for (int w2=0; w2<SCANWG; ++w2){
            const unsigned* pp = progS + w2*16;
            while ((int)ld_u32(pp) < t-20){ if (--bd < 0) break; }
          }
        }
        if (tid == 2 && (t&7)==0) st_u32(progS + wg*16, (unsigned)t);
      }
      __syncthreads();

      const uint32_t* hs = hb0 + (t&1)*256;
      float acch = 0.f;
      #pragma unroll
      for (int i=0;i<64;++i){
        uint4 hv = *(const uint4*)(hs + 4*i);
        acch = FDOT2(Wh[4*i+0], u2h2(hv.x), acch);
        acch = FDOT2(Wh[4*i+1], u2h2(hv.y), acch);
        acch = FDOT2(Wh[4*i+2], u2h2(hv.z), acch);
        acch = FDOT2(Wh[4*i+3], u2h2(hv.w), acch);
      }
      const uint32_t* xs = xb + (t&1)*64;
      float accx = 0.f;
      #pragma unroll
      for (int i=0;i<16;++i){
        uint4 xv = *(const uint4*)(xs + 4*i);
        accx = FDOT2(Wx[4*i+0], u2h2(xv.x), accx);
        accx = FDOT2(Wx[4*i+1], u2h2(xv.y), accx);
        accx = FDOT2(Wx[4*i+2], u2h2(xv.z), accx);
        accx = FDOT2(Wx[4*i+3], u2h2(xv.w), accx);
      }
      const float A = acch + bh;           // hh-part (incl bhh)
      const float B = accx + bi;           // ih-part (incl bih)
      const float Ar = dppx<DPP_B0>(A), Az = dppx<DPP_B1>(A), An = dppx<DPP_B2>(A);
      const float Br = dppx<DPP_B0>(B), Bz = dppx<DPP_B1>(B), Bn = dppx<DPP_B2>(B);
      const float r = sigmoidf_(Br + Ar);
      const float z = sigmoidf_(Bz + Az);
      const float n = tanhf_(Bn + r*An);
      const float h = (1.f - z)*n + z*hreg;
      hreg = h;
      const float h1v = __shfl_xor(h, 4, 64);   // h(o+1)
      if ((lane & 7) == 0){
        st_a64(ring0 + (size_t)(t&31)*256 + (obase>>1) + wv*8 + (rg>>1),
               ((unsigned long long)(unsigned)(t+1) << 32) | pack2h(h, h1v));
      }
      if (t == TSTEPS-1 && c == 0) hnext[o] = h;
    }
  } else if (wg < SCANWG){
    // ===================== layer 1 =====================
    const int q = wg - L0N;
    const int qbase = q*32;
    const int o = qbase + wv*8 + (rg>>1);
    const int slot = rg & 1;               // 0: Whh1 (dot h1), 1: Wih1 (dot h0)
    const int g = (c < 3) ? c : 2;
    h2 W[256];
    {
      const float* M = slot ? Wih1 : Whh1;
      const float4* r4 = (const float4*)(M + (size_t)(g*512 + o)*512);
      #pragma unroll
      for (int i=0;i<128;++i){
        float4 v = r4[i];
        W[2*i]   = h2{(_Float16)v.x,(_Float16)v.y};
        W[2*i+1] = h2{(_Float16)v.z,(_Float16)v.w};
      }
    }
    float hreg = hprev[512+o];
    const float bb = slot ? bih1[g*512+o] : bhh1[g*512+o];
    hb1[tid] = pack2h(hprev[512+2*tid], hprev[512+2*tid+1]);

    for (int s=0; s<TSTEPS; ++s){
      {
        const unsigned long long* p = ring0 + (size_t)(s&31)*256 + tid;
        unsigned long long v;
        for(;;){ v = ld_a64(p); if ((unsigned)(v>>32) == (unsigned)(s+1)) break;
                 if (--bd < 0) break; }
        hb0[(s&1)*256 + tid] = (uint32_t)v;
      }
      if (s > 0){
        const unsigned long long* p = ring1 + (size_t)((s-1)&31)*256 + tid;
        unsigned long long v;
        for(;;){ v = ld_a64(p); if ((unsigned)(v>>32) == (unsigned)s) break;
                 if (--bd < 0) break; }
        hb1[(s&1)*256 + tid] = (uint32_t)v;
      }
      if (tid == 0 && (s&7)==0 && s >= 32){
        for (int w2=L0N; w2<SCANWG; ++w2){
          const unsigned* pp = progS + w2*16;
          while ((int)ld_u32(pp) < s-20){ if (--bd < 0) break; }
        }
      }
      if (tid == 2 && (s&7)==0 && s > 0) st_u32(progS + wg*16, (unsigned)s);
      if (tid == 3 && (s&15)==0 && s > 0) st_rel(progH + q*16, (unsigned)(s-1));
      __syncthreads();

      const uint32_t* hs = (slot ? hb0 : hb1) + (s&1)*256;
      float acc = 0.f;
      #pragma unroll
      for (int i=0;i<64;++i){
        uint4 hv = *(const uint4*)(hs + 4*i);
        acc = FDOT2(W[4*i+0], u2h2(hv.x), acc);
        acc = FDOT2(W[4*i+1], u2h2(hv.y), acc);
        acc = FDOT2(W[4*i+2], u2h2(hv.z), acc);
        acc = FDOT2(W[4*i+3], u2h2(hv.w), acc);
      }
      const float A = acc + bb;
      const float Ar = dppx<DPP_B0>(A), Az = dppx<DPP_B1>(A), An = dppx<DPP_B2>(A);
      const float Xr = __shfl_xor(Ar, 4, 64);
      const float Xz = __shfl_xor(Az, 4, 64);
      const float Xn = __shfl_xor(An, 4, 64);
      const float hh_r = slot ? Xr : Ar, ih_r = slot ? Ar : Xr;
      const float hh_z = slot ? Xz : Az, ih_z = slot ? Az : Xz;
      const float hh_n = slot ? Xn : An, ih_n = slot ? An : Xn;
      const float r = sigmoidf_(ih_r + hh_r);
      const float z = sigmoidf_(ih_z + hh_z);
      const float n = tanhf_(ih_n + r*hh_n);
      const float h = (1.f - z)*n + z*hreg;
      hreg = h;
      const float ho1 = __shfl_xor(h, 8, 64);
      if ((lane & 15) == 0){
        st_a64(ring1 + (size_t)(s&31)*256 + (qbase>>1) + wv*4 + (rg>>2),
               ((unsigned long long)(unsigned)(s+1) << 32) | pack2h(h, ho1));
      }
      if ((lane & 7) == 0) H1[(size_t)s*512 + o] = h;
      if (s == TSTEPS-1 && (lane & 7) == 0) hnext[512+o] = h;
    }
    __syncthreads();
    if (tid == 3) st_rel(progH + q*16, (unsigned)TSTEPS);
  } else {
    // ===================== FC GEMM (pipelined) =====================
    float* Asd = (float*)smem;          // [32][68]
    float* Bsd = Asd + 32*68;
    int*   comm = (int*)(smem + 17408);
    const int tm = tid>>4, tn = tid&15, m0 = tid>>2, kk0 = (tid&3)*8;
    for(;;){
      if (tid == 0) comm[0] = (int)atomicAdd(ticket, 1u);
      __syncthreads();
      const int tau = comm[0];
      if (tau >= 4096) break;
      const int bm = tau >> 6, bn = tau & 63;
      if (tid == 0){
        const unsigned need = (unsigned)(bm*64 + 64);
        for(;;){
          unsigned mn = 0xFFFFFFFFu;
          for (int w2=0; w2<L1N; ++w2){
            unsigned v = ld_acq(progH + w2*16);
            mn = (v < mn) ? v : mn;
          }
          if (mn >= need) break;
          __builtin_amdgcn_s_sleep(32);
          if (--bd < 0) break;
        }
      }
      __syncthreads();

      const float* A = H1 + (size_t)bm*64*512;
      const float* B = Wfc + (size_t)bn*64*512;
      float acc[4][4] = {};
      for (int k0=0; k0<512; k0+=32){
        #pragma unroll
        for (int j=0;j<8;++j) Asd[(kk0+j)*68 + m0] = A[(size_t)m0*512 + k0+kk0+j];
        #pragma unroll
        for (int j=0;j<8;++j) Bsd[(kk0+j)*68 + m0] = B[(size_t)m0*512 + k0+kk0+j];
        __syncthreads();
        #pragma unroll
        for (int kk=0;kk<32;++kk){
          const float4 av = *(const float4*)&Asd[kk*68 + tm*4];
          const float4 bv = *(const float4*)&Bsd[kk*68 + tn*4];
          acc[0][0]=fmaf(av.x,bv.x,acc[0][0]); acc[0][1]=fmaf(av.x,bv.y,acc[0][1]);
          acc[0][2]=fmaf(av.x,bv.z,acc[0][2]); acc[0][3]=fmaf(av.x,bv.w,acc[0][3]);
          acc[1][0]=fmaf(av.y,bv.x,acc[1][0]); acc[1][1]=fmaf(av.y,bv.y,acc[1][1]);
          acc[1][2]=fmaf(av.y,bv.z,acc[1][2]); acc[1][3]=fmaf(av.y,bv.w,acc[1][3]);
          acc[2][0]=fmaf(av.z,bv.x,acc[2][0]); acc[2][1]=fmaf(av.z,bv.y,acc[2][1]);
          acc[2][2]=fmaf(av.z,bv.z,acc[2][2]); acc[2][3]=fmaf(av.z,bv.w,acc[2][3]);
          acc[3][0]=fmaf(av.w,bv.x,acc[3][0]); acc[3][1]=fmaf(av.w,bv.y,acc[3][1]);
          acc[3][2]=fmaf(av.w,bv.z,acc[3][2]); acc[3][3]=fmaf(av.w,bv.w,acc[3][3]);
        }
        __syncthreads();
      }
      #pragma unroll
      for (int i=0;i<4;++i){
        #pragma unroll
        for (int j=0;j<4;++j){
          const int mm = bm*64 + tm*4 + i;
          const int cc = bn*64 + tn*4 + j;
          float v = acc[i][j] + bfc[cc];
          v = fmaxf(v, 0.f);
          if (mask[cc] == 0) v = NEG_VAL;
          out[(size_t)mm*4096 + cc] = v;
        }
      }
    }
  }
}

// ---------------- launch ----------------
extern "C" void kernel_launch(void* const* d_in, const int* in_sizes, int n_in,
                              void* d_out, int out_size, void* d_ws, size_t ws_size,
                              hipStream_t stream)
{
  const float* state = (const float*)d_in[0];   // (4096, 129)
  const float* hprev = (const float*)d_in[1];   // (2, 512)
  const int*   mask  = (const int*)d_in[2];     // (64, 64)
  const float* Wih0  = (const float*)d_in[3];   // (1536, 128)
  const float* Whh0  = (const float*)d_in[4];   // (1536, 512)
  const float* bih0  = (const float*)d_in[5];
  const float* bhh0  = (const float*)d_in[6];
  const float* Wih1  = (const float*)d_in[7];   // (1536, 512)
  const float* Whh1  = (const float*)d_in[8];   // (1536, 512)
  const float* bih1  = (const float*)d_in[9];
  const float* bhh1  = (const float*)d_in[10];
  const float* Wfc   = (const float*)d_in[11];  // (4096, 512)
  const float* bfc   = (const float*)d_in[12];

  if (ws_size < WS_NEED) return;

  float* out = (float*)d_out;
  char*  ws  = (char*)d_ws;
  float* H1  = (float*)(ws + H1_OFF);
  unsigned long long* ring0 = (unsigned long long*)(ws + RING0_OFF);
  unsigned long long* ring1 = (unsigned long long*)(ws + RING1_OFF);
  unsigned* progS  = (unsigned*)(ws + PROGS_OFF);
  unsigned* progH  = (unsigned*)(ws + PROGH_OFF);
  unsigned* ticket = (unsigned*)(ws + TICK_OFF);

  // reset rings/progress/ticket every call (graph replays reuse ws)
  (void)hipMemsetAsync(ws + RING0_OFF, 0, (size_t)(WS_NEED - RING0_OFF), stream);

  actor_fused<<<GRIDWG, 256, 0, stream>>>(
      state, hprev, mask, Wih0, Whh0, bih0, bhh0,
      Wih1, Whh1, bih1, bhh1, Wfc, bfc,
      H1, ring0, ring1, progS, progH, ticket,
      out, out + (size_t)4096*4096);
}

// Round 5
// 21781.628 us; speedup vs baseline: 4.9855x; 2.0493x over previous
//
#include <hip/hip_runtime.h>
#include <stdint.h>

#define TS 4096
#define NEG_VAL -1000000000.0f

typedef _Float16 h2 __attribute__((ext_vector_type(2)));
typedef unsigned long long u64t;

// ---------------- workspace layout (bytes) ----------------
#define GI0_OFF   ((size_t)0)                         // 4096*1536*4 = 25165824
#define H1_OFF    ((size_t)TS*1536*4)                 // 4096*512*4  = 8388608
#define R0_OFF    (H1_OFF + (size_t)TS*512*4)         // 16*128*8 = 16384
#define R1_OFF    (R0_OFF + (size_t)16*128*8)         // 16384
#define GIR_OFF   (R1_OFF + (size_t)16*128*8)         // 16*1536*4 = 98304
#define TAG0_OFF  (GIR_OFF + (size_t)16*1536*4)       // 16*8*4 = 512
#define TAG1_OFF  (TAG0_OFF + 512)
#define TAGG_OFF  (TAG1_OFF + 512)
#define PROGS_OFF (TAGG_OFF + 512)                    // 24 u32 (pad 128)
#define PROGH_OFF (PROGS_OFF + 128)                   // 8 u32 (pad 64)
#define TICK_OFF  (PROGH_OFF + 64)
#define WS_NEED   (TICK_OFF + 64)

// ---------------- helpers ----------------
static __device__ __forceinline__ u64t ld_a64(const u64t* p){
  return __hip_atomic_load(p, __ATOMIC_RELAXED, __HIP_MEMORY_SCOPE_AGENT);
}
static __device__ __forceinline__ void st_a64(u64t* p, u64t v){
  __hip_atomic_store(p, v, __ATOMIC_RELAXED, __HIP_MEMORY_SCOPE_AGENT);
}
static __device__ __forceinline__ unsigned ld_u32(const unsigned* p){
  return __hip_atomic_load(p, __ATOMIC_RELAXED, __HIP_MEMORY_SCOPE_AGENT);
}
static __device__ __forceinline__ void st_u32(unsigned* p, unsigned v){
  __hip_atomic_store(p, v, __ATOMIC_RELAXED, __HIP_MEMORY_SCOPE_AGENT);
}
static __device__ __forceinline__ float sigmoidf_(float x){
  return 1.0f / (1.0f + __expf(-x));
}
static __device__ __forceinline__ float tanhf_(float x){
  float ax = fabsf(x);
  float e  = __expf(-2.0f*ax);
  float t  = (1.0f - e) / (1.0f + e);
  return copysignf(t, x);
}
static __device__ __forceinline__ uint32_t pack2h(float a, float b){
  _Float16 ha = (_Float16)a, hb = (_Float16)b;
  unsigned short ua = __builtin_bit_cast(unsigned short, ha);
  unsigned short ub = __builtin_bit_cast(unsigned short, hb);
  return (uint32_t)ua | ((uint32_t)ub << 16);
}
static __device__ __forceinline__ u64t pk4(float a, float b, float c, float d){
  return (u64t)pack2h(a,b) | ((u64t)pack2h(c,d) << 32);
}
static __device__ __forceinline__ h2 u2h2(uint32_t u){ return __builtin_bit_cast(h2, u); }

template<int CTRL>
static __device__ __forceinline__ float dppx(float x){
  return __int_as_float(__builtin_amdgcn_update_dpp(0, __float_as_int(x), CTRL, 0xF, 0xF, true));
}
static __device__ __forceinline__ float qsum8(float x){
  x += dppx<0xB1>(x);              // xor 1 (quad_perm 1,0,3,2)
  x += dppx<0x4E>(x);              // xor 2 (quad_perm 2,3,0,1)
  x += __shfl_xor(x, 4, 64);       // xor 4
  return x;
}

#if __has_builtin(__builtin_amdgcn_fdot2)
#define FDOT2(a,b,c) __builtin_amdgcn_fdot2((a),(b),(c),false)
#else
static __device__ __forceinline__ float FDOT2(h2 a, h2 b, float c){
  return c + (float)a[0]*(float)b[0] + (float)a[1]*(float)b[1];
}
#endif

// dot of 3 register-resident 32-h2 rows against 16 packed ring words
static __device__ __forceinline__ void dot96(const h2 (&w)[96], const u64t* base,
                                             float& s0, float& s1, float& s2){
  u64t d[16];
  #pragma unroll
  for (int i=0;i<16;++i) d[i] = ld_a64(base + i);
  float a0=0.f, a1=0.f, a2=0.f;
  #pragma unroll
  for (int i=0;i<16;++i){
    h2 lo = u2h2((uint32_t)d[i]);
    h2 hi = u2h2((uint32_t)(d[i]>>32));
    a0 = FDOT2(w[2*i],    lo, a0);  a0 = FDOT2(w[2*i+1],    hi, a0);
    a1 = FDOT2(w[32+2*i], lo, a1);  a1 = FDOT2(w[32+2*i+1], hi, a1);
    a2 = FDOT2(w[64+2*i], lo, a2);  a2 = FDOT2(w[64+2*i+1], hi, a2);
  }
  s0=a0; s1=a1; s2=a2;
}
// load one 32-h2 (64-col) segment of a weight row into registers (f32 -> f16)
static __device__ __forceinline__ void loadseg(h2* dst, const float* row, int col){
  const float4* p = (const float4*)(row + col);
  #pragma unroll
  for (int k=0;k<16;++k){
    float4 v = p[k];
    dst[2*k]   = h2{(_Float16)v.x, (_Float16)v.y};
    dst[2*k+1] = h2{(_Float16)v.z, (_Float16)v.w};
  }
}

// ================= fused kernel: 256 WGs x 512 thr =================
// WG 0..7  : layer0 core   (Whh0; 64 outputs each; 8 lanes/output)
// WG 8..15 : layer1 core   (Whh1; 64 outputs each)
// WG 16..23: gi1 helpers   (Wih1; rows {o,512+o,1024+o})
// WG 24..255: FC GEMM workers (128x64 tiles, ticketed, gated on progH)
__global__ __launch_bounds__(512,1) void actor_fused(
    const float* __restrict__ hprev,
    const int*   __restrict__ mask,
    const float* __restrict__ Whh0,
    const float* __restrict__ bhh0,
    const float* __restrict__ Wih1,
    const float* __restrict__ Whh1,
    const float* __restrict__ bih1,
    const float* __restrict__ bhh1,
    const float* __restrict__ Wfc,
    const float* __restrict__ bfc,
    const float* __restrict__ gi0,
    float* __restrict__ H1,
    u64t* ring0, u64t* ring1, unsigned* gir,
    unsigned* tag0, unsigned* tag1, unsigned* tagG,
    unsigned* progS, unsigned* progH, unsigned* ticket,
    float* __restrict__ out, float* __restrict__ hnext)
{
  const int wg  = blockIdx.x;
  const int tid = threadIdx.x;
  __shared__ __align__(16) float lds[6408];   // FC staging (scan WGs unused)
  long bd = 1L<<21;

  if (wg < 8){
    // ===================== layer 0 core =====================
    const int o = wg*64 + (tid>>3);
    const int j = tid&7;
    h2 w[96];
    loadseg(&w[0],  Whh0 + (size_t)o*512,          64*j);
    loadseg(&w[32], Whh0 + (size_t)(512+o)*512,    64*j);
    loadseg(&w[64], Whh0 + (size_t)(1024+o)*512,   64*j);
    const float br = bhh0[o], bz = bhh0[512+o], bn = bhh0[1024+o];
    float hreg = hprev[o];
    // prologue: h0(-1) -> ring0 slot 15, tag 1
    if (tid < 16){
      const float* hp = hprev + wg*64 + 4*tid;
      st_a64(ring0 + 15*128 + wg*16 + tid, pk4(hp[0],hp[1],hp[2],hp[3]));
    }
    asm volatile("s_waitcnt vmcnt(0)" ::: "memory");
    __syncthreads();
    if (tid==0) st_u32(tag0 + 15*8 + wg, 1u);

    for (int t=0; t<TS; ++t){
      if ((t&3)==0 && t>=16){                 // ring0 overwrite safety
        const int need = t-12;
        for(;;){
          int mn = 0x7fffffff;
          #pragma unroll
          for (int k=0;k<8;++k){ int v=(int)ld_u32(progS+k);    mn = v<mn?v:mn; }
          #pragma unroll
          for (int k=16;k<24;++k){ int v=(int)ld_u32(progS+k);  mn = v<mn?v:mn; }
          if (mn >= need) break;
          if (--bd < 0) break;
        }
      }
      const float* gp = gi0 + (size_t)t*1536;  // includes bih0
      const float gr = gp[o], gz = gp[512+o], gn = gp[1024+o];

      const int rs = (t-1)&15;
      const unsigned want = (unsigned)(t+1);
      { const unsigned* tp = tag0 + rs*8 + j;
        for(;;){ if (ld_u32(tp) == want) break; if (--bd < 0) break; } }

      float ar, az, an;
      dot96(w, ring0 + (size_t)rs*128 + 16*j, ar, az, an);
      ar = qsum8(ar); az = qsum8(az); an = qsum8(an);

      if (tid==4 && (t&3)==0) st_u32(progS + wg, (unsigned)t);

      const float r = sigmoidf_(gr + ar + br);
      const float z = sigmoidf_(gz + az + bz);
      const float n = tanhf_(gn + r*(an + bn));
      const float h = (1.f - z)*n + z*hreg;
      hreg = h;

      const float hb2 = __shfl_xor(h, 8, 64);
      const uint32_t p01 = pack2h(h, hb2);
      const uint32_t p23 = (uint32_t)__shfl_xor((int)p01, 16, 64);
      if ((tid&31)==0)
        st_a64(ring0 + (size_t)(t&15)*128 + wg*16 + (tid>>5),
               (u64t)p01 | ((u64t)p23<<32));
      if (t==TS-1 && j==0) hnext[o] = h;
      asm volatile("s_waitcnt vmcnt(0)" ::: "memory");
      __syncthreads();
      if (tid==0) st_u32(tag0 + (t&15)*8 + wg, (unsigned)(t+2));
    }
  } else if (wg < 16){
    // ===================== layer 1 core =====================
    const int q = wg-8;
    const int o = q*64 + (tid>>3);
    const int j = tid&7;
    h2 w[96];
    loadseg(&w[0],  Whh1 + (size_t)o*512,          64*j);
    loadseg(&w[32], Whh1 + (size_t)(512+o)*512,    64*j);
    loadseg(&w[64], Whh1 + (size_t)(1024+o)*512,   64*j);
    const float br = bhh1[o], bz = bhh1[512+o], bn = bhh1[1024+o];
    float hreg = hprev[512+o];
    if (tid < 16){
      const float* hp = hprev + 512 + q*64 + 4*tid;
      st_a64(ring1 + 15*128 + q*16 + tid, pk4(hp[0],hp[1],hp[2],hp[3]));
    }
    asm volatile("s_waitcnt vmcnt(0)" ::: "memory");
    __syncthreads();
    if (tid==0) st_u32(tag1 + 15*8 + q, 1u);

    for (int s=0; s<TS; ++s){
      if ((s&3)==0 && s>=16){                 // ring1 overwrite safety
        const int need = s-12;
        for(;;){
          int mn = 0x7fffffff;
          #pragma unroll
          for (int k=8;k<16;++k){ int v=(int)ld_u32(progS+k); mn = v<mn?v:mn; }
          if (mn >= need) break;
          if (--bd < 0) break;
        }
      }
      // gi1(s) from helpers (includes bih1)
      const int gs = s&15;
      { const unsigned* tp = tagG + gs*8 + q;
        const unsigned want = (unsigned)(s+1);
        for(;;){ if (ld_u32(tp) == want) break; if (--bd < 0) break; } }
      const float gr = __uint_as_float(ld_u32(gir + gs*1536 + o));
      const float gz = __uint_as_float(ld_u32(gir + gs*1536 + 512 + o));
      const float gn = __uint_as_float(ld_u32(gir + gs*1536 + 1024 + o));

      const int rs = (s-1)&15;
      { const unsigned* tp = tag1 + rs*8 + j;
        const unsigned want = (unsigned)(s+1);
        for(;;){ if (ld_u32(tp) == want) break; if (--bd < 0) break; } }

      float ar, az, an;
      dot96(w, ring1 + (size_t)rs*128 + 16*j, ar, az, an);
      ar = qsum8(ar); az = qsum8(az); an = qsum8(an);

      if (tid==4 && (s&3)==0) st_u32(progS + wg, (unsigned)s);

      const float r = sigmoidf_(gr + ar + br);
      const float z = sigmoidf_(gz + az + bz);
      const float n = tanhf_(gn + r*(an + bn));
      const float h = (1.f - z)*n + z*hreg;
      hreg = h;

      if (j==0)
        __hip_atomic_store(H1 + (size_t)s*512 + o, h,
                           __ATOMIC_RELAXED, __HIP_MEMORY_SCOPE_AGENT);
      const float hb2 = __shfl_xor(h, 8, 64);
      const uint32_t p01 = pack2h(h, hb2);
      const uint32_t p23 = (uint32_t)__shfl_xor((int)p01, 16, 64);
      if ((tid&31)==0)
        st_a64(ring1 + (size_t)(s&15)*128 + q*16 + (tid>>5),
               (u64t)p01 | ((u64t)p23<<32));
      if (s==TS-1 && j==0) hnext[512+o] = h;
      asm volatile("s_waitcnt vmcnt(0)" ::: "memory");
      __syncthreads();
      if (tid==0) st_u32(tag1 + (s&15)*8 + q, (unsigned)(s+2));
      if (tid==8 && (s&15)==15) st_u32(progH + q, (unsigned)(s+1));
    }
    __syncthreads();
    if (tid==8) st_u32(progH + q, (unsigned)TS);
  } else if (wg < 24){
    // ===================== gi1 helpers =====================
    const int hh = wg-16;
    const int o = hh*64 + (tid>>3);
    const int j = tid&7;
    h2 w[96];
    loadseg(&w[0],  Wih1 + (size_t)o*512,          64*j);
    loadseg(&w[32], Wih1 + (size_t)(512+o)*512,    64*j);
    loadseg(&w[64], Wih1 + (size_t)(1024+o)*512,   64*j);
    const float bia = (j<3) ? bih1[j*512+o] : 0.f;

    for (int s=0; s<TS; ++s){
      if ((s&3)==0 && s>=16){                 // gir overwrite safety
        const int need = s-12;
        for(;;){
          int mn = 0x7fffffff;
          #pragma unroll
          for (int k=8;k<16;++k){ int v=(int)ld_u32(progS+k); mn = v<mn?v:mn; }
          if (mn >= need) break;
          if (--bd < 0) break;
        }
      }
      const int rs = s&15;
      { const unsigned* tp = tag0 + rs*8 + j;
        const unsigned want = (unsigned)(s+2);
        for(;;){ if (ld_u32(tp) == want) break; if (--bd < 0) break; } }

      float g0, g1, g2;
      dot96(w, ring0 + (size_t)rs*128 + 16*j, g0, g1, g2);
      g0 = qsum8(g0); g1 = qsum8(g1); g2 = qsum8(g2);

      if (tid==4 && (s&3)==0) st_u32(progS + wg, (unsigned)s);

      if (j < 3){
        const float gv = ((j==0)?g0 : (j==1)?g1 : g2) + bia;
        st_u32(gir + rs*1536 + j*512 + o, __float_as_uint(gv));
      }
      asm volatile("s_waitcnt vmcnt(0)" ::: "memory");
      __syncthreads();
      if (tid==0) st_u32(tagG + rs*8 + hh, (unsigned)(s+1));
    }
  } else {
    // ===================== FC GEMM workers =====================
    float* As = lds;            // [32][132]
    float* Bs = lds + 32*132;   // [32][68]
    int*   comm = (int*)&lds[6404];
    const int tm = tid>>4, tn = tid&15;
    const int m0 = tid>>2, kk0a = (tid&3)*8;
    const int n0 = tid>>3, kk0b = (tid&7)*4;
    long fcbd = 1L<<24;
    for(;;){
      if (tid==0) comm[0] = (int)atomicAdd(ticket, 1u);
      __syncthreads();
      const int tau = comm[0];
      __syncthreads();
      if (tau >= 2048) break;
      const int bm = tau>>6, bn = tau&63;
      if (tid==0){
        const unsigned need = (unsigned)(bm*128 + 128);
        for(;;){
          unsigned mn = 0xffffffffu;
          #pragma unroll
          for (int k=0;k<8;++k){ unsigned v = ld_u32(progH+k); mn = v<mn?v:mn; }
          if (mn >= need) break;
          __builtin_amdgcn_s_sleep(16);
          if (--fcbd < 0) break;
        }
      }
      __syncthreads();

      const float* A = H1  + (size_t)bm*128*512;
      const float* B = Wfc + (size_t)bn*64*512;
      float acc[4][4] = {};
      for (int k0=0; k0<512; k0+=32){
        #pragma unroll
        for (int jj=0;jj<8;++jj) As[(kk0a+jj)*132 + m0] = A[(size_t)m0*512 + k0+kk0a+jj];
        #pragma unroll
        for (int jj=0;jj<4;++jj) Bs[(kk0b+jj)*68  + n0] = B[(size_t)n0*512 + k0+kk0b+jj];
        __syncthreads();
        #pragma unroll
        for (int kk=0;kk<32;++kk){
          const float4 av = *(const float4*)&As[kk*132 + tm*4];
          const float4 bv = *(const float4*)&Bs[kk*68  + tn*4];
          acc[0][0]=fmaf(av.x,bv.x,acc[0][0]); acc[0][1]=fmaf(av.x,bv.y,acc[0][1]);
          acc[0][2]=fmaf(av.x,bv.z,acc[0][2]); acc[0][3]=fmaf(av.x,bv.w,acc[0][3]);
          acc[1][0]=fmaf(av.y,bv.x,acc[1][0]); acc[1][1]=fmaf(av.y,bv.y,acc[1][1]);
          acc[1][2]=fmaf(av.y,bv.z,acc[1][2]); acc[1][3]=fmaf(av.y,bv.w,acc[1][3]);
          acc[2][0]=fmaf(av.z,bv.x,acc[2][0]); acc[2][1]=fmaf(av.z,bv.y,acc[2][1]);
          acc[2][2]=fmaf(av.z,bv.z,acc[2][2]); acc[2][3]=fmaf(av.z,bv.w,acc[2][3]);
          acc[3][0]=fmaf(av.w,bv.x,acc[3][0]); acc[3][1]=fmaf(av.w,bv.y,acc[3][1]);
          acc[3][2]=fmaf(av.w,bv.z,acc[3][2]); acc[3][3]=fmaf(av.w,bv.w,acc[3][3]);
        }
        __syncthreads();
      }
      const int cc0 = bn*64 + tn*4;
      const int mk0 = mask[cc0], mk1 = mask[cc0+1], mk2 = mask[cc0+2], mk3 = mask[cc0+3];
      const float b0 = bfc[cc0], b1 = bfc[cc0+1], b2 = bfc[cc0+2], b3 = bfc[cc0+3];
      #pragma unroll
      for (int i=0;i<4;++i){
        const int mm = bm*128 + tm*4 + i;
        float4 v;
        v.x = fmaxf(acc[i][0]+b0, 0.f); if (mk0==0) v.x = NEG_VAL;
        v.y = fmaxf(acc[i][1]+b1, 0.f); if (mk1==0) v.y = NEG_VAL;
        v.z = fmaxf(acc[i][2]+b2, 0.f); if (mk2==0) v.z = NEG_VAL;
        v.w = fmaxf(acc[i][3]+b3, 0.f); if (mk3==0) v.w = NEG_VAL;
        *(float4*)&out[(size_t)mm*4096 + cc0] = v;
      }
    }
  }
}

// ---------------- gi0 = state[:,1:] @ Wih0^T + bih0 (f32, proven r1) ----------------
__global__ __launch_bounds__(256) void gemm_gi0(
    const float* __restrict__ A, int lda,
    const float* __restrict__ B, int ldb,
    float* __restrict__ C, int ldc,
    const float* __restrict__ bias, int K)
{
  __shared__ __align__(16) float As[32][68];
  __shared__ __align__(16) float Bs[32][68];
  const int bm = blockIdx.y*64, bn = blockIdx.x*64;
  const int tid = threadIdx.x;
  const int tm = tid>>4, tn = tid&15;
  float acc[4][4] = {};
  const int m0 = tid>>2, kk0 = (tid&3)*8;
  for (int k0=0; k0<K; k0+=32){
    #pragma unroll
    for (int j=0;j<8;++j) As[kk0+j][m0] = A[(size_t)(bm+m0)*lda + k0+kk0+j];
    #pragma unroll
    for (int j=0;j<8;++j) Bs[kk0+j][m0] = B[(size_t)(bn+m0)*ldb + k0+kk0+j];
    __syncthreads();
    #pragma unroll
    for (int kk=0;kk<32;++kk){
      const float4 av = *(const float4*)&As[kk][tm*4];
      const float4 bv = *(const float4*)&Bs[kk][tn*4];
      acc[0][0]=fmaf(av.x,bv.x,acc[0][0]); acc[0][1]=fmaf(av.x,bv.y,acc[0][1]);
      acc[0][2]=fmaf(av.x,bv.z,acc[0][2]); acc[0][3]=fmaf(av.x,bv.w,acc[0][3]);
      acc[1][0]=fmaf(av.y,bv.x,acc[1][0]); acc[1][1]=fmaf(av.y,bv.y,acc[1][1]);
      acc[1][2]=fmaf(av.y,bv.z,acc[1][2]); acc[1][3]=fmaf(av.y,bv.w,acc[1][3]);
      acc[2][0]=fmaf(av.z,bv.x,acc[2][0]); acc[2][1]=fmaf(av.z,bv.y,acc[2][1]);
      acc[2][2]=fmaf(av.z,bv.z,acc[2][2]); acc[2][3]=fmaf(av.z,bv.w,acc[2][3]);
      acc[3][0]=fmaf(av.w,bv.x,acc[3][0]); acc[3][1]=fmaf(av.w,bv.y,acc[3][1]);
      acc[3][2]=fmaf(av.w,bv.z,acc[3][2]); acc[3][3]=fmaf(av.w,bv.w,acc[3][3]);
    }
    __syncthreads();
  }
  #pragma unroll
  for (int i=0;i<4;++i){
    #pragma unroll
    for (int j=0;j<4;++j){
      const int mm = bm + tm*4 + i, cc = bn + tn*4 + j;
      C[(size_t)mm*ldc + cc] = acc[i][j] + bias[cc];
    }
  }
}

// ---------------- launch ----------------
extern "C" void kernel_launch(void* const* d_in, const int* in_sizes, int n_in,
                              void* d_out, int out_size, void* d_ws, size_t ws_size,
                              hipStream_t stream)
{
  const float* state = (const float*)d_in[0];   // (4096, 129)
  const float* hprev = (const float*)d_in[1];   // (2, 512)
  const int*   mask  = (const int*)d_in[2];     // (64, 64)
  const float* Wih0  = (const float*)d_in[3];   // (1536, 128)
  const float* Whh0  = (const float*)d_in[4];   // (1536, 512)
  const float* bih0  = (const float*)d_in[5];
  const float* bhh0  = (const float*)d_in[6];
  const float* Wih1  = (const float*)d_in[7];   // (1536, 512)
  const float* Whh1  = (const float*)d_in[8];   // (1536, 512)
  const float* bih1  = (const float*)d_in[9];
  const float* bhh1  = (const float*)d_in[10];
  const float* Wfc   = (const float*)d_in[11];  // (4096, 512)
  const float* bfc   = (const float*)d_in[12];

  if (ws_size < WS_NEED) return;

  float* out = (float*)d_out;
  char*  ws  = (char*)d_ws;
  float* gi0 = (float*)(ws + GI0_OFF);
  float* H1  = (float*)(ws + H1_OFF);
  u64t*  ring0 = (u64t*)(ws + R0_OFF);
  u64t*  ring1 = (u64t*)(ws + R1_OFF);
  unsigned* gir   = (unsigned*)(ws + GIR_OFF);
  unsigned* tag0  = (unsigned*)(ws + TAG0_OFF);
  unsigned* tag1  = (unsigned*)(ws + TAG1_OFF);
  unsigned* tagG  = (unsigned*)(ws + TAGG_OFF);
  unsigned* progS = (unsigned*)(ws + PROGS_OFF);
  unsigned* progH = (unsigned*)(ws + PROGH_OFF);
  unsigned* tick  = (unsigned*)(ws + TICK_OFF);

  // clear rings/tags/progress/ticket each call (graph replays reuse ws)
  (void)hipMemsetAsync(ws + R0_OFF, 0, (size_t)(WS_NEED - R0_OFF), stream);

  // gi0 precompute: M=4096, N=1536, K=128
  {
    dim3 grid(1536/64, 4096/64);
    gemm_gi0<<<grid, 256, 0, stream>>>(state+1, 129, Wih0, 128, gi0, 1536, bih0, 128);
  }

  actor_fused<<<256, 512, 0, stream>>>(
      hprev, mask, Whh0, bhh0, Wih1, Whh1, bih1, bhh1, Wfc, bfc,
      gi0, H1, ring0, ring1, gir, tag0, tag1, tagG, progS, progH, tick,
      out, out + (size_t)4096*4096);
}